// Round 1
// baseline (71.756 us; speedup 1.0000x reference)
//
#include <hip/hip_runtime.h>
#include <hip/hip_bf16.h>

typedef __attribute__((ext_vector_type(8))) __bf16 bf16x8;
typedef __attribute__((ext_vector_type(4))) float f32x4;

namespace {

constexpr int L     = 2048;   // query length (== S)
constexpr int E     = 64;     // embed dim == value dim
constexpr int H     = 8;      // heads in memory layout
constexpr int NHEAD = 16;     // B*H reinterpreted heads
constexpr int QBLK  = 64;     // q rows per block (4 waves x 16)
constexpr int KVB   = 64;     // kv rows per tile
constexpr int STR   = 72;     // LDS row stride (bf16 elems), +8 pad
constexpr float SCALE = 0.125f;  // 1/sqrt(64)

// out[b,l,h,d] = sum_{s<=l} w(l,s) * V[b,s,h,d] / sum_{s<=l} w(l,s)
// w = exp(SCALE * (1 - exp(-max(|q|^2+|k|^2-2 q.k, 0))))
__global__ __launch_bounds__(256, 2)
void degr_attn_kernel(const float* __restrict__ Qg,
                      const float* __restrict__ Kg,
                      const float* __restrict__ Vg,
                      float* __restrict__ Og) {
  __shared__ __bf16 Qs[QBLK][STR];
  __shared__ __bf16 Ks[KVB][STR];
  __shared__ __bf16 Vt[E][STR];       // Vt[d][s]  (transposed V tile)
  __shared__ __bf16 Ps[4][16][STR];   // per-wave P tile (16 l x 64 s)
  __shared__ float qn_s[QBLK];
  __shared__ float kn_s[KVB];

  const int n  = blockIdx.y;                 // reinterpreted head 0..15
  const int b  = n >> 3;
  const int h  = n & 7;
  // load-balance remap: co-resident blocks (id, id+256) get complementary tiles
  const int lt = (blockIdx.y < 8) ? blockIdx.x : (31 - blockIdx.x);
  const int l0 = lt * QBLK;

  const int t    = threadIdx.x;
  const int wave = t >> 6;
  const int lane = t & 63;
  const int lg   = lane >> 4;   // lane group 0..3
  const int lr   = lane & 15;   // lane row/col 0..15

  const float* Qh = Qg + (size_t)n * (L * E);           // contiguous [2048][64]
  const float* Kh = Kg + (size_t)n * (L * E);
  const float* Vb = Vg + (size_t)b * L * (H * E) + h * E;  // row stride 512
  float*       Ob = Og + (size_t)b * L * (H * E) + h * E;

  const int sr  = t >> 2;  // staging row 0..63
  const int seg = t & 3;   // 16-float segment within row

  // ---- stage Q tile as bf16 + per-row |q|^2 ----
  {
    const float4* src = reinterpret_cast<const float4*>(
        Qh + (size_t)(l0 + sr) * E + seg * 16);
    float pn = 0.f;
    bf16x8 w0, w1;
    {
      float4 a = src[0], c = src[1];
      pn += a.x*a.x + a.y*a.y + a.z*a.z + a.w*a.w;
      pn += c.x*c.x + c.y*c.y + c.z*c.z + c.w*c.w;
      w0[0]=(__bf16)a.x; w0[1]=(__bf16)a.y; w0[2]=(__bf16)a.z; w0[3]=(__bf16)a.w;
      w0[4]=(__bf16)c.x; w0[5]=(__bf16)c.y; w0[6]=(__bf16)c.z; w0[7]=(__bf16)c.w;
    }
    {
      float4 a = src[2], c = src[3];
      pn += a.x*a.x + a.y*a.y + a.z*a.z + a.w*a.w;
      pn += c.x*c.x + c.y*c.y + c.z*c.z + c.w*c.w;
      w1[0]=(__bf16)a.x; w1[1]=(__bf16)a.y; w1[2]=(__bf16)a.z; w1[3]=(__bf16)a.w;
      w1[4]=(__bf16)c.x; w1[5]=(__bf16)c.y; w1[6]=(__bf16)c.z; w1[7]=(__bf16)c.w;
    }
    *reinterpret_cast<bf16x8*>(&Qs[sr][seg*16])     = w0;
    *reinterpret_cast<bf16x8*>(&Qs[sr][seg*16 + 8]) = w1;
    pn += __shfl_xor(pn, 1);
    pn += __shfl_xor(pn, 2);
    if (seg == 0) qn_s[sr] = pn;
  }
  __syncthreads();

  // Q A-fragments for this wave's 16 rows, kept in registers.
  // A layout (16x16x32): a[i] = A[lane%16][8*(lane/16) + i], per 32-wide K chunk.
  const bf16x8 qf0 = *reinterpret_cast<const bf16x8*>(&Qs[wave*16 + lr][lg*8]);
  const bf16x8 qf1 = *reinterpret_cast<const bf16x8*>(&Qs[wave*16 + lr][32 + lg*8]);
  float qn_r[4];
  #pragma unroll
  for (int r = 0; r < 4; ++r) qn_r[r] = qn_s[wave*16 + lg*4 + r];

  f32x4 oacc[4];
  #pragma unroll
  for (int i = 0; i < 4; ++i) oacc[i] = (f32x4){0.f, 0.f, 0.f, 0.f};
  float den[4] = {0.f, 0.f, 0.f, 0.f};

  for (int tk = 0; tk <= lt; ++tk) {
    const int s0 = tk * KVB;

    // ---- stage K tile + per-row |k|^2 ----
    {
      const float4* src = reinterpret_cast<const float4*>(
          Kh + (size_t)(s0 + sr) * E + seg * 16);
      float pn = 0.f;
      bf16x8 w0, w1;
      {
        float4 a = src[0], c = src[1];
        pn += a.x*a.x + a.y*a.y + a.z*a.z + a.w*a.w;
        pn += c.x*c.x + c.y*c.y + c.z*c.z + c.w*c.w;
        w0[0]=(__bf16)a.x; w0[1]=(__bf16)a.y; w0[2]=(__bf16)a.z; w0[3]=(__bf16)a.w;
        w0[4]=(__bf16)c.x; w0[5]=(__bf16)c.y; w0[6]=(__bf16)c.z; w0[7]=(__bf16)c.w;
      }
      {
        float4 a = src[2], c = src[3];
        pn += a.x*a.x + a.y*a.y + a.z*a.z + a.w*a.w;
        pn += c.x*c.x + c.y*c.y + c.z*c.z + c.w*c.w;
        w1[0]=(__bf16)a.x; w1[1]=(__bf16)a.y; w1[2]=(__bf16)a.z; w1[3]=(__bf16)a.w;
        w1[4]=(__bf16)c.x; w1[5]=(__bf16)c.y; w1[6]=(__bf16)c.z; w1[7]=(__bf16)c.w;
      }
      *reinterpret_cast<bf16x8*>(&Ks[sr][seg*16])     = w0;
      *reinterpret_cast<bf16x8*>(&Ks[sr][seg*16 + 8]) = w1;
      pn += __shfl_xor(pn, 1);
      pn += __shfl_xor(pn, 2);
      if (seg == 0) kn_s[sr] = pn;
    }
    // ---- stage V tile transposed: Vt[d][s] ----
    {
      const float4* src = reinterpret_cast<const float4*>(
          Vb + (size_t)(s0 + sr) * (H * E) + seg * 16);
      #pragma unroll
      for (int j = 0; j < 4; ++j) {
        float4 a = src[j];
        const int d = seg*16 + j*4;
        Vt[d+0][sr] = (__bf16)a.x;
        Vt[d+1][sr] = (__bf16)a.y;
        Vt[d+2][sr] = (__bf16)a.z;
        Vt[d+3][sr] = (__bf16)a.w;
      }
    }
    __syncthreads();

    // ---- QK^T -> w -> Ps (wave-private) ----
    #pragma unroll
    for (int ss = 0; ss < 4; ++ss) {
      // B layout: b[i] = B[8*(lane/16)+i][lane%16]; B = K^T so read K[s][e]
      const bf16x8 kf0 = *reinterpret_cast<const bf16x8*>(&Ks[ss*16 + lr][lg*8]);
      const bf16x8 kf1 = *reinterpret_cast<const bf16x8*>(&Ks[ss*16 + lr][32 + lg*8]);
      f32x4 acc = (f32x4){0.f, 0.f, 0.f, 0.f};
      acc = __builtin_amdgcn_mfma_f32_16x16x32_bf16(qf0, kf0, acc, 0, 0, 0);
      acc = __builtin_amdgcn_mfma_f32_16x16x32_bf16(qf1, kf1, acc, 0, 0, 0);
      const int   s_glob = s0 + ss*16 + lr;     // D col = lane%16
      const float kn_l   = kn_s[ss*16 + lr];
      #pragma unroll
      for (int r = 0; r < 4; ++r) {             // D row = 4*(lane/16)+r
        const int l_glob = l0 + wave*16 + lg*4 + r;
        float d2 = fmaxf(qn_r[r] + kn_l - 2.0f * acc[r], 0.f);
        float w  = (s_glob <= l_glob)
                     ? __expf(SCALE * (1.0f - __expf(-d2)))
                     : 0.0f;
        den[r] += w;
        Ps[wave][lg*4 + r][ss*16 + lr] = (__bf16)w;
      }
    }

    // ---- PV: out += P * V ----
    #pragma unroll
    for (int sc = 0; sc < 2; ++sc) {
      const bf16x8 pf = *reinterpret_cast<const bf16x8*>(&Ps[wave][lr][sc*32 + lg*8]);
      #pragma unroll
      for (int dsb = 0; dsb < 4; ++dsb) {
        const bf16x8 vf = *reinterpret_cast<const bf16x8*>(&Vt[dsb*16 + lr][sc*32 + lg*8]);
        oacc[dsb] = __builtin_amdgcn_mfma_f32_16x16x32_bf16(pf, vf, oacc[dsb], 0, 0, 0);
      }
    }
    __syncthreads();
  }

  // ---- epilogue: reduce den across the 16 lanes sharing each row, store ----
  #pragma unroll
  for (int r = 0; r < 4; ++r) {
    float dsum = den[r];
    dsum += __shfl_xor(dsum, 1);
    dsum += __shfl_xor(dsum, 2);
    dsum += __shfl_xor(dsum, 4);
    dsum += __shfl_xor(dsum, 8);
    const float inv = 1.0f / dsum;
    float* orow = Ob + (size_t)(l0 + wave*16 + lg*4 + r) * (H * E);
    #pragma unroll
    for (int dsb = 0; dsb < 4; ++dsb)
      orow[dsb*16 + lr] = oacc[dsb][r] * inv;
  }
}

} // namespace

extern "C" void kernel_launch(void* const* d_in, const int* in_sizes, int n_in,
                              void* d_out, int out_size, void* d_ws, size_t ws_size,
                              hipStream_t stream) {
  (void)in_sizes; (void)n_in; (void)out_size; (void)d_ws; (void)ws_size;
  const float* q = (const float*)d_in[0];
  const float* k = (const float*)d_in[1];
  const float* v = (const float*)d_in[2];
  float*       o = (float*)d_out;
  dim3 grid(L / QBLK, NHEAD);
  dim3 block(256);
  degr_attn_kernel<<<grid, block, 0, stream>>>(q, k, v, o);
}

// Round 2
// 54.960 us; speedup vs baseline: 1.3056x; 1.3056x over previous
//
#include <hip/hip_runtime.h>
#include <hip/hip_bf16.h>

typedef __attribute__((ext_vector_type(8))) __bf16 bf16x8;
typedef __attribute__((ext_vector_type(4))) float f32x4;

namespace {

constexpr int L = 2048;      // query length (== S)
constexpr int E = 64;        // embed dim == value dim
constexpr int NHEAD = 16;    // B*H reinterpreted heads
constexpr int QBLK = 64;     // q rows per block (4 waves x 16)
constexpr int KVB = 64;      // kv rows per tile
constexpr float SCALE = 0.125f;  // 1/sqrt(64)

// workspace layout (bytes)
constexpr size_t KN_OFF = 4096;                              // f32 [16][2048]
constexpr size_t KB_OFF = KN_OFF + (size_t)NHEAD * L * 4;    // bf16 [16][2048][64]
constexpr size_t VT_OFF = KB_OFF + (size_t)NHEAD * L * E * 2;// bf16 [16][64][2048]

// XOR swizzle within a 128-byte LDS row (bank-conflict-free ds_read_b128)
__device__ __forceinline__ int swz(int row, int byte_in_row) {
  return row * 128 + (byte_in_row ^ ((row & 7) << 4));
}

__device__ __forceinline__ void cvt_row16(const float4* src, float& pn,
                                          bf16x8& w0, bf16x8& w1) {
  float4 a = src[0], c = src[1];
  pn += a.x*a.x + a.y*a.y + a.z*a.z + a.w*a.w;
  pn += c.x*c.x + c.y*c.y + c.z*c.z + c.w*c.w;
  w0[0]=(__bf16)a.x; w0[1]=(__bf16)a.y; w0[2]=(__bf16)a.z; w0[3]=(__bf16)a.w;
  w0[4]=(__bf16)c.x; w0[5]=(__bf16)c.y; w0[6]=(__bf16)c.z; w0[7]=(__bf16)c.w;
  float4 d = src[2], e = src[3];
  pn += d.x*d.x + d.y*d.y + d.z*d.z + d.w*d.w;
  pn += e.x*e.x + e.y*e.y + e.z*e.z + e.w*e.w;
  w1[0]=(__bf16)d.x; w1[1]=(__bf16)d.y; w1[2]=(__bf16)d.z; w1[3]=(__bf16)d.w;
  w1[4]=(__bf16)e.x; w1[5]=(__bf16)e.y; w1[6]=(__bf16)e.z; w1[7]=(__bf16)e.w;
}

// ---- prep: K -> bf16 [n][s][e] + row norms (f32) ----
__global__ __launch_bounds__(256)
void prep_k(const float* __restrict__ Kg, __bf16* __restrict__ Kb,
            float* __restrict__ kn) {
  const int t = threadIdx.x;
  const int row = blockIdx.x * 64 + (t >> 2);   // 0 .. 32767
  const int seg = t & 3;
  const float4* src = reinterpret_cast<const float4*>(
      Kg + (size_t)row * E + seg * 16);
  float pn = 0.f; bf16x8 w0, w1;
  cvt_row16(src, pn, w0, w1);
  __bf16* dst = Kb + (size_t)row * E + seg * 16;
  *reinterpret_cast<bf16x8*>(dst)     = w0;
  *reinterpret_cast<bf16x8*>(dst + 8) = w1;
  pn += __shfl_xor(pn, 1);
  pn += __shfl_xor(pn, 2);
  if (seg == 0) kn[row] = pn;
}

// ---- prep: V -> bf16 transposed [n][d][s] ----
__global__ __launch_bounds__(256)
void prep_v(const float* __restrict__ Vg, __bf16* __restrict__ Vt) {
  __shared__ float Vs[64][65];
  const int n  = blockIdx.x >> 5;   // head 0..15
  const int st = blockIdx.x & 31;   // s-tile
  const int b = n >> 3, h = n & 7;
  const int t = threadIdx.x;
  {
    const int srow = t >> 2, seg = t & 3;
    const float4* src = reinterpret_cast<const float4*>(
        Vg + ((size_t)b * L + st * 64 + srow) * 512 + h * 64 + seg * 16);
    #pragma unroll
    for (int j = 0; j < 4; ++j) {
      float4 a = src[j];
      Vs[srow][seg*16 + j*4 + 0] = a.x;
      Vs[srow][seg*16 + j*4 + 1] = a.y;
      Vs[srow][seg*16 + j*4 + 2] = a.z;
      Vs[srow][seg*16 + j*4 + 3] = a.w;
    }
  }
  __syncthreads();
  {
    const int d = t >> 2, sg = t & 3;
    bf16x8 o0, o1;
    #pragma unroll
    for (int i = 0; i < 8; ++i) o0[i] = (__bf16)Vs[sg*16 + i][d];
    #pragma unroll
    for (int i = 0; i < 8; ++i) o1[i] = (__bf16)Vs[sg*16 + 8 + i][d];
    __bf16* dst = Vt + (size_t)n * (E * L) + (size_t)d * L + st * 64 + sg * 16;
    *reinterpret_cast<bf16x8*>(dst)     = o0;
    *reinterpret_cast<bf16x8*>(dst + 8) = o1;
  }
}

// ---- main attention ----
__global__ __launch_bounds__(256, 2)
void degr_attn(const float* __restrict__ Qg, const __bf16* __restrict__ Kb,
               const __bf16* __restrict__ Vt, const float* __restrict__ kng,
               float* __restrict__ Og) {
  __shared__ __bf16 Qs[QBLK * 64];
  __shared__ __bf16 Ks[2][KVB * 64];
  __shared__ __bf16 Vs[2][E * KVB];
  __shared__ __bf16 Ps[4][16 * 64];
  __shared__ float  kns[2][KVB];
  __shared__ float  qn_s[QBLK];

  // schedule: ids c and c+256 share a CU (XCD round-robin) -> same head,
  // complementary l-tiles => uniform 33 KV-tile-steps per CU, 2 heads/XCD.
  const int bi = blockIdx.x;
  const int c  = bi & 255, pq = bi >> 8;
  const int n  = c & 15;
  const int x  = c >> 4;
  const int lt = pq ? 31 - x : x;
  const int l0 = lt * QBLK;
  const int b = n >> 3, h = n & 7;

  const int t = threadIdx.x;
  const int wave = t >> 6, lane = t & 63;
  const int lg = lane >> 4, lr = lane & 15;

  const float*  Qh  = Qg  + (size_t)n * (L * E);
  const __bf16* Kh  = Kb  + (size_t)n * (L * E);
  const __bf16* Vh  = Vt  + (size_t)n * (E * L);
  const float*  knh = kng + (size_t)n * L;
  float*        Ob  = Og  + (size_t)b * L * 512 + h * 64;

  // ---- stage Q tile (f32 -> bf16, swizzled) + row norms ----
  {
    const int row = t >> 2, seg = t & 3;
    const float4* src = reinterpret_cast<const float4*>(
        Qh + (size_t)(l0 + row) * E + seg * 16);
    float pn = 0.f; bf16x8 w0, w1;
    cvt_row16(src, pn, w0, w1);
    *reinterpret_cast<bf16x8*>((char*)Qs + swz(row, seg*32))      = w0;
    *reinterpret_cast<bf16x8*>((char*)Qs + swz(row, seg*32 + 16)) = w1;
    pn += __shfl_xor(pn, 1);
    pn += __shfl_xor(pn, 2);
    if (seg == 0) qn_s[row] = pn;
  }
  __syncthreads();

  const bf16x8 qf0 = *reinterpret_cast<const bf16x8*>(
      (const char*)Qs + swz(wave*16 + lr, lg*16));
  const bf16x8 qf1 = *reinterpret_cast<const bf16x8*>(
      (const char*)Qs + swz(wave*16 + lr, 64 + lg*16));
  float qn_r[4];
  #pragma unroll
  for (int r = 0; r < 4; ++r) qn_r[r] = qn_s[wave*16 + lg*4 + r];

  // ---- staging regs (double-buffered pipeline) ----
  const int srow = t >> 2;          // K row s / V row d
  const int scol = (t & 3) * 2;     // 16B-chunk pair index
  bf16x8 kr0, kr1, vr0, vr1; float knv = 0.f;

  auto loadKV = [&](int s0) {
    const __bf16* kp = Kh + (size_t)(s0 + srow) * E + scol * 8;
    kr0 = *reinterpret_cast<const bf16x8*>(kp);
    kr1 = *reinterpret_cast<const bf16x8*>(kp + 8);
    const __bf16* vp = Vh + (size_t)srow * L + s0 + scol * 8;
    vr0 = *reinterpret_cast<const bf16x8*>(vp);
    vr1 = *reinterpret_cast<const bf16x8*>(vp + 8);
    if (t < KVB) knv = knh[s0 + t];
  };
  auto writeKV = [&](int buf) {
    *reinterpret_cast<bf16x8*>((char*)Ks[buf] + swz(srow, scol*16))      = kr0;
    *reinterpret_cast<bf16x8*>((char*)Ks[buf] + swz(srow, scol*16 + 16)) = kr1;
    *reinterpret_cast<bf16x8*>((char*)Vs[buf] + swz(srow, scol*16))      = vr0;
    *reinterpret_cast<bf16x8*>((char*)Vs[buf] + swz(srow, scol*16 + 16)) = vr1;
    if (t < KVB) kns[buf][t] = knv;
  };

  loadKV(0);
  writeKV(0);
  __syncthreads();

  f32x4 oacc[4];
  #pragma unroll
  for (int i = 0; i < 4; ++i) oacc[i] = (f32x4){0.f, 0.f, 0.f, 0.f};
  float den[4] = {0.f, 0.f, 0.f, 0.f};

  for (int tk = 0; tk <= lt; ++tk) {
    const int  cur  = tk & 1;
    const bool more = (tk < lt);
    if (more) loadKV((tk + 1) * KVB);   // issue early; in flight across compute

    __builtin_amdgcn_s_setprio(1);
    // ---- QK^T -> w -> Ps ----
    #pragma unroll
    for (int ss = 0; ss < 4; ++ss) {
      const int krow = ss*16 + lr;
      const bf16x8 kf0 = *reinterpret_cast<const bf16x8*>(
          (const char*)Ks[cur] + swz(krow, lg*16));
      const bf16x8 kf1 = *reinterpret_cast<const bf16x8*>(
          (const char*)Ks[cur] + swz(krow, 64 + lg*16));
      f32x4 acc = (f32x4){0.f, 0.f, 0.f, 0.f};
      acc = __builtin_amdgcn_mfma_f32_16x16x32_bf16(qf0, kf0, acc, 0, 0, 0);
      acc = __builtin_amdgcn_mfma_f32_16x16x32_bf16(qf1, kf1, acc, 0, 0, 0);
      const float kn_l   = kns[cur][krow];
      const int   s_glob = tk*KVB + krow;
      #pragma unroll
      for (int r = 0; r < 4; ++r) {
        const int lq = lg*4 + r;
        const int l_glob = l0 + wave*16 + lq;
        float d2 = fmaxf(qn_r[r] + kn_l - 2.0f * acc[r], 0.f);
        float w  = (s_glob <= l_glob)
                     ? __expf(SCALE * (1.0f - __expf(-d2)))
                     : 0.0f;
        den[r] += w;
        *reinterpret_cast<__bf16*>(
            (char*)Ps[wave] + lq*128 + ((krow*2) ^ ((lq & 7) << 4))) = (__bf16)w;
      }
    }
    // ---- PV ----
    #pragma unroll
    for (int sc = 0; sc < 2; ++sc) {
      const bf16x8 pf = *reinterpret_cast<const bf16x8*>(
          (const char*)Ps[wave] + lr*128 + ((sc*64 + lg*16) ^ ((lr & 7) << 4)));
      #pragma unroll
      for (int dsb = 0; dsb < 4; ++dsb) {
        const bf16x8 vf = *reinterpret_cast<const bf16x8*>(
            (const char*)Vs[cur] + swz(dsb*16 + lr, sc*64 + lg*16));
        oacc[dsb] = __builtin_amdgcn_mfma_f32_16x16x32_bf16(pf, vf, oacc[dsb], 0, 0, 0);
      }
    }
    __builtin_amdgcn_s_setprio(0);
    __syncthreads();
    if (more) writeKV(cur ^ 1);
    __syncthreads();
  }

  // ---- epilogue ----
  #pragma unroll
  for (int r = 0; r < 4; ++r) {
    float dsum = den[r];
    dsum += __shfl_xor(dsum, 1);
    dsum += __shfl_xor(dsum, 2);
    dsum += __shfl_xor(dsum, 4);
    dsum += __shfl_xor(dsum, 8);
    const float inv = 1.0f / dsum;
    float* orow = Ob + (size_t)(l0 + wave*16 + lg*4 + r) * 512;
    #pragma unroll
    for (int dsb = 0; dsb < 4; ++dsb)
      orow[dsb*16 + lr] = oacc[dsb][r] * inv;
  }
}

} // namespace

extern "C" void kernel_launch(void* const* d_in, const int* in_sizes, int n_in,
                              void* d_out, int out_size, void* d_ws, size_t ws_size,
                              hipStream_t stream) {
  (void)in_sizes; (void)n_in; (void)out_size; (void)ws_size;
  const float* q = (const float*)d_in[0];
  const float* k = (const float*)d_in[1];
  const float* v = (const float*)d_in[2];
  float*       o = (float*)d_out;

  char* ws = (char*)d_ws;
  float*  kn = (float*)(ws + KN_OFF);
  __bf16* Kb = (__bf16*)(ws + KB_OFF);
  __bf16* Vt = (__bf16*)(ws + VT_OFF);

  prep_k<<<dim3(512), dim3(256), 0, stream>>>(k, Kb, kn);
  prep_v<<<dim3(512), dim3(256), 0, stream>>>(v, Vt);
  degr_attn<<<dim3(512), dim3(256), 0, stream>>>(q, Kb, Vt, kn, o);
}